// Round 15
// baseline (492.567 us; speedup 1.0000x reference)
//
#include <hip/hip_runtime.h>
#include <hip/hip_cooperative_groups.h>

namespace cg = cooperative_groups;

typedef unsigned short u16;
typedef unsigned int u32;
typedef unsigned long long u64;

#define N_NODES 100000
#define N_EDGES 600000
#define D 128
#define NPG 1000
#define NGRAPH 100
#define VOCAB 32000
#define MBW 3136          // mask words (padded) >= ceil(100000/32)

#define CAP_SLOTS 65536
#define CAP_L1    16384
#define CAP_L2    4096
#define CAP_E2    16384
#define CAP_E3    4096

#define C_SLOT 0
#define C_L1   1
#define C_L2   2
#define C_E2   3
#define C_E3   4
#define C64    8          // int-index of packed u64 alloc counter (8-aligned)

#define NPK (192 * 128)          // packed W u32 per job
#define EMBP_U32 (VOCAB * 64)    // bf16-packed embedding table, u32 count
#define ZWORDS (64 + 2 * MBW)    // ctrl + mb1 + mb2 in u32 words

__device__ __forceinline__ float bf2f(u16 u) {
  return __uint_as_float(((u32)u) << 16);
}
__device__ __forceinline__ u16 f2bf(float f) {
  u32 u = __float_as_uint(f);
  u32 r = (u + 0x7FFFu + ((u >> 16) & 1u)) >> 16;  // RNE
  return (u16)r;
}
__device__ __forceinline__ u32 packbf2(float a, float b) {
  return (u32)f2bf(a) | ((u32)f2bf(b) << 16);
}
__device__ __forceinline__ void fma4(float4& acc, float a, const float4 w) {
  acc.x = fmaf(a, w.x, acc.x);
  acc.y = fmaf(a, w.y, acc.y);
  acc.z = fmaf(a, w.z, acc.z);
  acc.w = fmaf(a, w.w, acc.w);
}
__device__ __forceinline__ float4 bf4(uint2 u) {
  return make_float4(bf2f((u16)(u.x & 0xFFFFu)), bf2f((u16)(u.x >> 16)),
                     bf2f((u16)(u.y & 0xFFFFu)), bf2f((u16)(u.y >> 16)));
}
__device__ __forceinline__ void add4(float4& a, const float4 b) {
  a.x += b.x; a.y += b.y; a.z += b.z; a.w += b.w;
}
__device__ __forceinline__ float4 shfl4(float4 v, int lane) {
  return make_float4(__shfl(v.x, lane, 32), __shfl(v.y, lane, 32),
                     __shfl(v.z, lane, 32), __shfl(v.w, lane, 32));
}
__device__ __forceinline__ int mbit(const u32* __restrict__ mb, int n) {
  return (mb[n >> 5] >> (n & 31)) & 1u;
}
__device__ __forceinline__ void mset(u32* __restrict__ mb, int n) {
  atomicOr(&mb[n >> 5], 1u << (n & 31));
}

struct MegaArgs {
  const int* tok;
  const int4* src4;
  const int4* dst4;
  const float* attr;
  const float* emb;
  const float* wproj;
  const float* bproj;
  const float *ws1, *bs1, *wm1, *bm1, *we1, *be1;
  const float *ws2, *bs2, *wm2, *bm2, *we2, *be2;
  const float *ws3, *bs3, *wm3, *bm3;
  float* out;
  int* ctrl;
  u32* mb1;
  u32* mb2;
  int* deg;
  int* offn;
  int* cur;
  int2* csr_se;
  int* csr_dst;
  int4* E2;
  int4* E3;
  int* L1;
  int* L2;
  float* degf;
  u32 *w1p, *e1p, *w2p, *e2p, *w3p;
  u32* embp;
  u16* A_n;
  u16* A_e;
  float* x1;
  float* x2;
  u16* ea;
};

// ================= phase device functions (shared by coop + fallback) =======

// P0: zero ctrl/masks/deg; pack 5 weight buffers + emb table to bf16
__device__ void ph_setup(const MegaArgs& A, int gtid, int nthr) {
  for (int i = gtid; i < ZWORDS; i += nthr) ((u32*)A.ctrl)[i] = 0;
  for (int i = gtid; i < N_NODES; i += nthr) A.deg[i] = 0;
  for (int t = gtid; t < 5 * NPK; t += nthr) {
    int buf = t / NPK, elem = t % NPK;
    int k2 = elem >> 7, c = elem & 127;
    int k0 = 2 * k2, k1 = 2 * k2 + 1;
    float a, b;
    u32* dst;
    if (buf == 0) {
      a = k0 < 128 ? A.ws1[k0 * 128 + c] : A.wm1[(k0 - 128) * 128 + c];
      b = k1 < 128 ? A.ws1[k1 * 128 + c] : A.wm1[(k1 - 128) * 128 + c];
      dst = A.w1p;
    } else if (buf == 1) {
      a = A.we1[k0 * 128 + c]; b = A.we1[k1 * 128 + c]; dst = A.e1p;
    } else if (buf == 2) {
      a = k0 < 128 ? A.ws2[k0 * 128 + c] : A.wm2[(k0 - 128) * 128 + c];
      b = k1 < 128 ? A.ws2[k1 * 128 + c] : A.wm2[(k1 - 128) * 128 + c];
      dst = A.w2p;
    } else if (buf == 3) {
      a = A.we2[k0 * 128 + c]; b = A.we2[k1 * 128 + c]; dst = A.e2p;
    } else {
      a = k0 < 128 ? A.ws3[k0 * 128 + c] : A.wm3[(k0 - 128) * 128 + c];
      b = k1 < 128 ? A.ws3[k1 * 128 + c] : A.wm3[(k1 - 128) * 128 + c];
      dst = A.w3p;
    }
    dst[elem] = packbf2(a, b);
  }
  for (int i = gtid; i < EMBP_U32; i += nthr) {
    float2 e2 = ((const float2*)A.emb)[i];
    A.embp[i] = packbf2(e2.x, e2.y);
  }
}

__device__ void ph_scan3(const MegaArgs& A, int gtid, int nthr) {
  if (gtid < NGRAPH) {
    mset(A.mb2, gtid * NPG);
    mset(A.mb1, gtid * NPG);
  }
  for (int i = gtid; i < N_EDGES / 4; i += nthr) {
    int4 d = A.dst4[i], s = A.src4[i];
    if (d.x % NPG == 0) { mset(A.mb2, s.x); mset(A.mb1, s.x); }
    if (d.y % NPG == 0) { mset(A.mb2, s.y); mset(A.mb1, s.y); }
    if (d.z % NPG == 0) { mset(A.mb2, s.z); mset(A.mb1, s.z); }
    if (d.w % NPG == 0) { mset(A.mb2, s.w); mset(A.mb1, s.w); }
  }
}

__device__ void ph_scan2(const MegaArgs& A, int gtid, int nthr) {
  for (int i = gtid; i < N_EDGES / 4; i += nthr) {
    int4 d = A.dst4[i], s = A.src4[i];
    if (mbit(A.mb2, d.x)) mset(A.mb1, s.x);
    if (mbit(A.mb2, d.y)) mset(A.mb1, s.y);
    if (mbit(A.mb2, d.z)) mset(A.mb1, s.z);
    if (mbit(A.mb2, d.w)) mset(A.mb1, s.w);
  }
}

__device__ void ph_scan1(const MegaArgs& A, int gtid, int nthr) {
  for (int i = gtid; i < N_EDGES / 4; i += nthr) {
    int4 d = A.dst4[i];
    if (mbit(A.mb1, d.x)) atomicAdd(&A.deg[d.x], 1);
    if (mbit(A.mb1, d.y)) atomicAdd(&A.deg[d.y], 1);
    if (mbit(A.mb1, d.z)) atomicAdd(&A.deg[d.z], 1);
    if (mbit(A.mb1, d.w)) atomicAdd(&A.deg[d.w], 1);
  }
}

// P4: CSR alloc — block bid handles nodes [bid*1024, bid*1024+1024), 4/thread,
// ONE packed-u64 atomic per block. ash = 16 shared ints.
__device__ void ph_alloc(const MegaArgs& A, int bid, int tid, int* ash) {
  int* asum = ash;       // [4] wave sums (then exclusive bases)
  int* acnt1 = ash + 4;
  int* acnt2 = ash + 8;
  int* abase = ash + 12; // [3]
  int lane = tid & 63, wid = tid >> 6;
  int base = bid * 1024 + tid * 4;
  bool m1v[4], m2v[4];
  int dv[4];
  int degs = 0, c1 = 0, c2 = 0;
#pragma unroll
  for (int j = 0; j < 4; ++j) {
    int n = base + j;
    bool in = n < N_NODES;
    m1v[j] = in && mbit(A.mb1, n);
    m2v[j] = in && mbit(A.mb2, n);
    dv[j] = m1v[j] ? A.deg[n] : 0;
    degs += dv[j];
    c1 += (int)m1v[j];
    c2 += (int)m2v[j];
  }
  int sI = degs, c1I = c1, c2I = c2;
#pragma unroll
  for (int o = 1; o < 64; o <<= 1) {
    int a = __shfl_up(sI, o, 64);
    int b = __shfl_up(c1I, o, 64);
    int c = __shfl_up(c2I, o, 64);
    if (lane >= o) { sI += a; c1I += b; c2I += c; }
  }
  if (lane == 63) { asum[wid] = sI; acnt1[wid] = c1I; acnt2[wid] = c2I; }
  __syncthreads();
  if (tid == 0) {
    int s0 = 0, s1 = 0, s2 = 0;
    int wb0[4], wb1[4], wb2[4];
#pragma unroll
    for (int w = 0; w < 4; ++w) {
      wb0[w] = s0; wb1[w] = s1; wb2[w] = s2;
      s0 += asum[w]; s1 += acnt1[w]; s2 += acnt2[w];
    }
    u64 pk = (u64)s0 | ((u64)s1 << 24) | ((u64)s2 << 44);
    u64 old = atomicAdd((u64*)(A.ctrl + C64), pk);
    abase[0] = (int)(old & 0xFFFFFF);
    abase[1] = (int)((old >> 24) & 0xFFFFF);
    abase[2] = (int)(old >> 44);
#pragma unroll
    for (int w = 0; w < 4; ++w) { asum[w] = wb0[w]; acnt1[w] = wb1[w]; acnt2[w] = wb2[w]; }
  }
  __syncthreads();
  int myoff = abase[0] + asum[wid] + (sI - degs);
  int myc1 = abase[1] + acnt1[wid] + (c1I - c1);
  int myc2 = abase[2] + acnt2[wid] + (c2I - c2);
#pragma unroll
  for (int j = 0; j < 4; ++j) {
    int n = base + j;
    if (m1v[j]) {
      A.offn[n] = myoff;
      A.cur[n] = myoff;
      myoff += dv[j];
      if (myc1 < CAP_L1) A.L1[myc1] = n;
      myc1++;
    }
    if (m2v[j]) {
      if (myc2 < CAP_L2) A.L2[myc2] = n;
      myc2++;
    }
  }
}

// P5: scatter edges into CSR (distributed cur atomics); thread 0 unpacks totals
__device__ void ph_scatter(const MegaArgs& A, int gtid, int nthr) {
  if (gtid == 0) {
    u64 pk = *(const u64*)(A.ctrl + C64);
    A.ctrl[C_SLOT] = (int)(pk & 0xFFFFFF);
    A.ctrl[C_L1] = (int)((pk >> 24) & 0xFFFFF);
    A.ctrl[C_L2] = (int)(pk >> 44);
  }
  for (int i = gtid; i < N_EDGES / 4; i += nthr) {
    int4 dv = A.dst4[i], sv = A.src4[i];
    int ds[4] = {dv.x, dv.y, dv.z, dv.w};
    int ss[4] = {sv.x, sv.y, sv.z, sv.w};
#pragma unroll
    for (int j = 0; j < 4; ++j) {
      int d = ds[j];
      if (!mbit(A.mb1, d)) continue;
      int p = atomicAdd(&A.cur[d], 1);
      if (p < CAP_SLOTS) {
        A.csr_se[p] = make_int2(ss[j], i * 4 + j);
        A.csr_dst[p] = d;
      }
    }
  }
}

// P6: build E2/E3 packed lists {p, src, dst, e}
__device__ void ph_lists(const MegaArgs& A, int gtid, int nthr) {
  int lane = threadIdx.x & 63;
  int ns = A.ctrl[C_SLOT];
  if (ns > CAP_SLOTS) ns = CAP_SLOTS;
  int total = (ns + 63) & ~63;
  for (int p = gtid; p < total; p += nthr) {
    bool inb = p < ns;
    int d = inb ? A.csr_dst[p] : 0;
    bool e2 = inb && mbit(A.mb2, d);
    bool e3 = inb && (d % NPG == 0);
    int2 se = (e2 || e3) ? A.csr_se[p] : make_int2(0, 0);
    u64 bal = __ballot(e2);
    if (bal) {
      int base = 0;
      if (lane == 0) base = atomicAdd(&A.ctrl[C_E2], __popcll(bal));
      base = __shfl(base, 0, 64);
      int pos = __popcll(bal & ((1ull << lane) - 1ull));
      if (e2 && base + pos < CAP_E2) A.E2[base + pos] = make_int4(p, se.x, d, se.y);
    }
    u64 bal3 = __ballot(e3);
    if (bal3) {
      int base = 0;
      if (lane == 0) base = atomicAdd(&A.ctrl[C_E3], __popcll(bal3));
      base = __shfl(base, 0, 64);
      int pos = __popcll(bal3 & ((1ull << lane) - 1ull));
      if (e3 && base + pos < CAP_E3) A.E3[base + pos] = make_int4(p, se.x, d, se.y);
    }
  }
}

// ---- gathers: build bf16 A rows ----

__device__ __forceinline__ void store_seg(u16* Ar, int seg, int q, float4 v) {
  ((uint2*)Ar)[seg * 32 + q] = make_uint2(packbf2(v.x, v.y), packbf2(v.z, v.w));
}

__device__ void dev_gather_node(const MegaArgs& A, bool l1, const int* L, int n_,
                                int relBlk, int nBlk, const float* xin, u16* An) {
  int sub = threadIdx.x >> 5, q = threadIdx.x & 31;
  for (int i = relBlk * 8 + sub; i < n_; i += nBlk * 8) {
    int n = L ? L[i] : i * NPG;
    int o = A.offn[n], end = A.cur[n];
    float dgf = (float)(end - o);
    float4 sx = make_float4(0.f, 0.f, 0.f, 0.f);
    float4 se = make_float4(0.f, 0.f, 0.f, 0.f);
    float4 xn;
    if (l1) {
      float4 sa = make_float4(0.f, 0.f, 0.f, 0.f);
      for (int p = o; p < end; ++p) {
        int2 s2 = A.csr_se[p];
        add4(sx, bf4(((const uint2*)A.embp)[(size_t)A.tok[s2.x] * 32 + q]));
        add4(sa, ((const float4*)(A.attr + (size_t)s2.y * 16))[q & 3]);
      }
      float4 bp = ((const float4*)A.bproj)[q];
      se = make_float4(bp.x * dgf, bp.y * dgf, bp.z * dgf, bp.w * dgf);
      const float4* wp = (const float4*)A.wproj;
#pragma unroll
      for (int k4 = 0; k4 < 4; ++k4) {
        float4 xv = shfl4(sa, k4);
        fma4(se, xv.x, wp[(k4 * 4 + 0) * 32 + q]);
        fma4(se, xv.y, wp[(k4 * 4 + 1) * 32 + q]);
        fma4(se, xv.z, wp[(k4 * 4 + 2) * 32 + q]);
        fma4(se, xv.w, wp[(k4 * 4 + 3) * 32 + q]);
      }
      xn = bf4(((const uint2*)A.embp)[(size_t)A.tok[n] * 32 + q]);
    } else {
      for (int p = o; p < end; ++p) {
        int s = A.csr_se[p].x;
        add4(sx, ((const float4*)(xin + (size_t)s * D))[q]);
        add4(se, bf4(((const uint2*)(A.ea + (size_t)p * D))[q]));
      }
      xn = ((const float4*)(xin + (size_t)n * D))[q];
    }
    u16* Ar = An + (size_t)i * 384;
    store_seg(Ar, 0, q, xn);
    store_seg(Ar, 1, q, sx);
    store_seg(Ar, 2, q, se);
    if (q == 0) A.degf[i] = dgf;
  }
}

__device__ void dev_gather_edge(const MegaArgs& A, bool l1, const int4* EL, int n_,
                                int relBlk, int nBlk, const float* xin, u16* Ae) {
  int sub = threadIdx.x >> 5, q = threadIdx.x & 31;
  for (int i = relBlk * 8 + sub; i < n_; i += nBlk * 8) {
    int4 t = EL[i];
    int p = t.x, s = t.y, d = t.z, e = t.w;
    float4 xd, xs, ev;
    if (l1) {
      xd = bf4(((const uint2*)A.embp)[(size_t)A.tok[d] * 32 + q]);
      xs = bf4(((const uint2*)A.embp)[(size_t)A.tok[s] * 32 + q]);
      float4 av = ((const float4*)(A.attr + (size_t)e * 16))[q & 3];
      ev = ((const float4*)A.bproj)[q];
      const float4* wp = (const float4*)A.wproj;
#pragma unroll
      for (int k4 = 0; k4 < 4; ++k4) {
        float4 xv = shfl4(av, k4);
        fma4(ev, xv.x, wp[(k4 * 4 + 0) * 32 + q]);
        fma4(ev, xv.y, wp[(k4 * 4 + 1) * 32 + q]);
        fma4(ev, xv.z, wp[(k4 * 4 + 2) * 32 + q]);
        fma4(ev, xv.w, wp[(k4 * 4 + 3) * 32 + q]);
      }
    } else {
      xd = ((const float4*)(xin + (size_t)d * D))[q];
      xs = ((const float4*)(xin + (size_t)s * D))[q];
      ev = bf4(((const uint2*)(A.ea + (size_t)p * D))[q]);
    }
    u16* Ar = Ae + (size_t)i * 384;
    store_seg(Ar, 0, q, xd);
    store_seg(Ar, 1, q, xs);
    store_seg(Ar, 2, q, ev);
  }
}

// ---- W-resident bf16 GEMM (one (job,col-half) per block) ----

#define ASF(x) __uint_as_float(x)

__device__ void dev_gemm(uint4* Wl4, uint4* Al4, const u16* Ab, const u32* W,
                         const float* biasp, const float* bmp, const float* degf,
                         const int* L, const int4* EL, float* outf, u16* outb,
                         int M, int relu, int half, int lid, int cnt) {
  int nt = (M + 15) >> 4;
  if (lid >= nt) return;   // block-uniform
  int q = threadIdx.x & 63, wv = threadIdx.x >> 6;
  const u32* Wlds = (const u32*)Wl4;
#pragma unroll
  for (int u = 0; u < 12; ++u) {
    int idx = threadIdx.x + u * 256;
    int k2 = idx >> 4, c4 = idx & 15;
    Wl4[idx] = ((const uint4*)W)[k2 * 32 + half * 16 + c4];
  }
  float bias = biasp[half * 64 + q];
  float bmv = degf ? bmp[half * 64 + q] : 0.f;
  for (int t = lid; t < nt; t += cnt) {
    __syncthreads();
#pragma unroll
    for (int u = 0; u < 3; ++u) {
      int idx = threadIdx.x + u * 256;
      int row = idx / 48, c8 = idx % 48;
      int gr = t * 16 + row;
      if (gr > M - 1) gr = M - 1;
      Al4[idx] = ((const uint4*)(Ab + (size_t)gr * 384))[c8];
    }
    __syncthreads();
    const uint2* A0 = (const uint2*)Al4 + (wv * 4 + 0) * 96;
    const uint2* A1 = (const uint2*)Al4 + (wv * 4 + 1) * 96;
    const uint2* A2 = (const uint2*)Al4 + (wv * 4 + 2) * 96;
    const uint2* A3 = (const uint2*)Al4 + (wv * 4 + 3) * 96;
    float acc0 = bias, acc1 = bias, acc2 = bias, acc3 = bias;
#pragma unroll 8
    for (int k4 = 0; k4 < 96; ++k4) {
      u32 wA = Wlds[(k4 * 2) * 64 + q];
      u32 wB = Wlds[(k4 * 2 + 1) * 64 + q];
      float wk0 = ASF(wA << 16), wk1 = ASF(wA & 0xffff0000u);
      float wk2 = ASF(wB << 16), wk3 = ASF(wB & 0xffff0000u);
      uint2 a;
      a = A0[k4];
      acc0 = fmaf(ASF(a.x << 16), wk0, acc0);
      acc0 = fmaf(ASF(a.x & 0xffff0000u), wk1, acc0);
      acc0 = fmaf(ASF(a.y << 16), wk2, acc0);
      acc0 = fmaf(ASF(a.y & 0xffff0000u), wk3, acc0);
      a = A1[k4];
      acc1 = fmaf(ASF(a.x << 16), wk0, acc1);
      acc1 = fmaf(ASF(a.x & 0xffff0000u), wk1, acc1);
      acc1 = fmaf(ASF(a.y << 16), wk2, acc1);
      acc1 = fmaf(ASF(a.y & 0xffff0000u), wk3, acc1);
      a = A2[k4];
      acc2 = fmaf(ASF(a.x << 16), wk0, acc2);
      acc2 = fmaf(ASF(a.x & 0xffff0000u), wk1, acc2);
      acc2 = fmaf(ASF(a.y << 16), wk2, acc2);
      acc2 = fmaf(ASF(a.y & 0xffff0000u), wk3, acc2);
      a = A3[k4];
      acc3 = fmaf(ASF(a.x << 16), wk0, acc3);
      acc3 = fmaf(ASF(a.x & 0xffff0000u), wk1, acc3);
      acc3 = fmaf(ASF(a.y << 16), wk2, acc3);
      acc3 = fmaf(ASF(a.y & 0xffff0000u), wk3, acc3);
    }
    float accs[4] = {acc0, acc1, acc2, acc3};
#pragma unroll
    for (int r = 0; r < 4; ++r) {
      int row = t * 16 + wv * 4 + r;
      if (row < M) {
        float a = accs[r];
        if (degf) a = fmaf(degf[row], bmv, a);
        if (relu) a = fmaxf(a, 0.f);
        if (outb) {
          int p = EL[row].x;
          outb[(size_t)p * D + half * 64 + q] = f2bf(a);
        } else {
          int idx = L ? L[row] : row;
          outf[(size_t)idx * D + half * 64 + q] = a;
        }
      }
    }
  }
}

// ---- per-stage wrappers ----

__device__ void ph_gather1(const MegaArgs& A, int bid, int nb) {
  int nL1 = A.ctrl[C_L1]; if (nL1 > CAP_L1) nL1 = CAP_L1;
  int nE2 = A.ctrl[C_E2]; if (nE2 > CAP_E2) nE2 = CAP_E2;
  int hf = nb >> 1;
  if (bid < hf) dev_gather_node(A, true, A.L1, nL1, bid, hf, nullptr, A.A_n);
  else dev_gather_edge(A, true, A.E2, nE2, bid - hf, nb - hf, nullptr, A.A_e);
}
__device__ void ph_gemm1(const MegaArgs& A, uint4* Wl4, uint4* Al4, int bid, int nb) {
  int nL1 = A.ctrl[C_L1]; if (nL1 > CAP_L1) nL1 = CAP_L1;
  int nE2 = A.ctrl[C_E2]; if (nE2 > CAP_E2) nE2 = CAP_E2;
  int job = (bid & 2) >> 1, half = bid & 1, lid = bid >> 2, cnt = nb >> 2;
  if (job == 0)
    dev_gemm(Wl4, Al4, A.A_n, A.w1p, A.bs1, A.bm1, A.degf, A.L1, nullptr,
             A.x1, nullptr, nL1, 1, half, lid, cnt);
  else
    dev_gemm(Wl4, Al4, A.A_e, A.e1p, A.be1, nullptr, nullptr, nullptr, A.E2,
             nullptr, A.ea, nE2, 1, half, lid, cnt);
}
__device__ void ph_gather2(const MegaArgs& A, int bid, int nb) {
  int nL2 = A.ctrl[C_L2]; if (nL2 > CAP_L2) nL2 = CAP_L2;
  int nE3 = A.ctrl[C_E3]; if (nE3 > CAP_E3) nE3 = CAP_E3;
  int hf = nb >> 1;
  if (bid < hf) dev_gather_node(A, false, A.L2, nL2, bid, hf, A.x1, A.A_n);
  else dev_gather_edge(A, false, A.E3, nE3, bid - hf, nb - hf, A.x1, A.A_e);
}
__device__ void ph_gemm2(const MegaArgs& A, uint4* Wl4, uint4* Al4, int bid, int nb) {
  int nL2 = A.ctrl[C_L2]; if (nL2 > CAP_L2) nL2 = CAP_L2;
  int nE3 = A.ctrl[C_E3]; if (nE3 > CAP_E3) nE3 = CAP_E3;
  int job = (bid & 2) >> 1, half = bid & 1, lid = bid >> 2, cnt = nb >> 2;
  if (job == 0)
    dev_gemm(Wl4, Al4, A.A_n, A.w2p, A.bs2, A.bm2, A.degf, A.L2, nullptr,
             A.x2, nullptr, nL2, 1, half, lid, cnt);
  else
    dev_gemm(Wl4, Al4, A.A_e, A.e2p, A.be2, nullptr, nullptr, nullptr, A.E3,
             nullptr, A.ea, nE3, 1, half, lid, cnt);
}
__device__ void ph_gather3(const MegaArgs& A, int bid, int nb) {
  int hf = nb >> 1;
  if (bid < hf) dev_gather_node(A, false, nullptr, NGRAPH, bid, hf, A.x2, A.A_n);
}
__device__ void ph_gemm3(const MegaArgs& A, uint4* Wl4, uint4* Al4, int bid, int nb) {
  int half = bid & 1, lid = bid >> 1, cnt = nb >> 1;
  dev_gemm(Wl4, Al4, A.A_n, A.w3p, A.bs3, A.bm3, A.degf, nullptr, nullptr,
           A.out, nullptr, NGRAPH, 0, half, lid, cnt);
}

// ================= cooperative mega-kernel =================

__global__ __launch_bounds__(256, 2) void k_mega(MegaArgs A) {
  __shared__ uint4 Wl4[3072];   // 48 KB
  __shared__ uint4 Al4[768];    // 12 KB
  __shared__ int ash[16];
  cg::grid_group grid = cg::this_grid();
  int tid = threadIdx.x, bid = blockIdx.x, nb = gridDim.x;
  int gtid = bid * 256 + tid, nthr = nb * 256;

  ph_setup(A, gtid, nthr);   grid.sync();
  ph_scan3(A, gtid, nthr);   grid.sync();
  ph_scan2(A, gtid, nthr);   grid.sync();
  ph_scan1(A, gtid, nthr);   grid.sync();
  if (bid < 98) ph_alloc(A, bid, tid, ash);
  grid.sync();
  ph_scatter(A, gtid, nthr); grid.sync();
  ph_lists(A, gtid, nthr);   grid.sync();
  ph_gather1(A, bid, nb);    grid.sync();
  ph_gemm1(A, Wl4, Al4, bid, nb); grid.sync();
  ph_gather2(A, bid, nb);    grid.sync();
  ph_gemm2(A, Wl4, Al4, bid, nb); grid.sync();
  ph_gather3(A, bid, nb);    grid.sync();
  ph_gemm3(A, Wl4, Al4, bid, nb);
}

// ================= fallback: phases as individual kernels =================

__global__ __launch_bounds__(256) void k_f_setup(MegaArgs A) {
  ph_setup(A, blockIdx.x * 256 + threadIdx.x, gridDim.x * 256);
}
__global__ __launch_bounds__(256) void k_f_scan3(MegaArgs A) {
  ph_scan3(A, blockIdx.x * 256 + threadIdx.x, gridDim.x * 256);
}
__global__ __launch_bounds__(256) void k_f_scan2(MegaArgs A) {
  ph_scan2(A, blockIdx.x * 256 + threadIdx.x, gridDim.x * 256);
}
__global__ __launch_bounds__(256) void k_f_scan1(MegaArgs A) {
  ph_scan1(A, blockIdx.x * 256 + threadIdx.x, gridDim.x * 256);
}
__global__ __launch_bounds__(256) void k_f_alloc(MegaArgs A) {  // grid = 98
  __shared__ int ash[16];
  ph_alloc(A, blockIdx.x, threadIdx.x, ash);
}
__global__ __launch_bounds__(256) void k_f_scatter(MegaArgs A) {
  ph_scatter(A, blockIdx.x * 256 + threadIdx.x, gridDim.x * 256);
}
__global__ __launch_bounds__(256) void k_f_lists(MegaArgs A) {
  ph_lists(A, blockIdx.x * 256 + threadIdx.x, gridDim.x * 256);
}
__global__ __launch_bounds__(256) void k_f_gather1(MegaArgs A) {
  ph_gather1(A, blockIdx.x, gridDim.x);
}
__global__ __launch_bounds__(256, 2) void k_f_gemm1(MegaArgs A) {
  __shared__ uint4 Wl4[3072];
  __shared__ uint4 Al4[768];
  ph_gemm1(A, Wl4, Al4, blockIdx.x, gridDim.x);
}
__global__ __launch_bounds__(256) void k_f_gather2(MegaArgs A) {
  ph_gather2(A, blockIdx.x, gridDim.x);
}
__global__ __launch_bounds__(256, 2) void k_f_gemm2(MegaArgs A) {
  __shared__ uint4 Wl4[3072];
  __shared__ uint4 Al4[768];
  ph_gemm2(A, Wl4, Al4, blockIdx.x, gridDim.x);
}
__global__ __launch_bounds__(256) void k_f_gather3(MegaArgs A) {
  ph_gather3(A, blockIdx.x, gridDim.x);
}
__global__ __launch_bounds__(256, 2) void k_f_gemm3(MegaArgs A) {
  __shared__ uint4 Wl4[3072];
  __shared__ uint4 Al4[768];
  ph_gemm3(A, Wl4, Al4, blockIdx.x, gridDim.x);
}

extern "C" void kernel_launch(void* const* d_in, const int* in_sizes, int n_in,
                              void* d_out, int out_size, void* d_ws, size_t ws_size,
                              hipStream_t stream) {
  MegaArgs a;
  a.tok = (const int*)d_in[0];
  const int* eidx = (const int*)d_in[1];
  a.src4 = (const int4*)eidx;
  a.dst4 = (const int4*)(eidx + N_EDGES);
  a.attr = (const float*)d_in[2];
  a.emb = (const float*)d_in[4];
  a.wproj = (const float*)d_in[5];
  a.bproj = (const float*)d_in[6];
  a.ws1 = (const float*)d_in[7];  a.bs1 = (const float*)d_in[8];
  a.wm1 = (const float*)d_in[9];  a.bm1 = (const float*)d_in[10];
  a.we1 = (const float*)d_in[11]; a.be1 = (const float*)d_in[12];
  a.ws2 = (const float*)d_in[13]; a.bs2 = (const float*)d_in[14];
  a.wm2 = (const float*)d_in[15]; a.bm2 = (const float*)d_in[16];
  a.we2 = (const float*)d_in[17]; a.be2 = (const float*)d_in[18];
  a.ws3 = (const float*)d_in[19]; a.bs3 = (const float*)d_in[20];
  a.wm3 = (const float*)d_in[21]; a.bm3 = (const float*)d_in[22];
  a.out = (float*)d_out;

  char* base = (char*)d_ws;
  size_t o = 0;
  a.ctrl = (int*)(base + o); o += 256;
  a.mb1 = (u32*)(base + o); o += MBW * 4;
  a.mb2 = (u32*)(base + o); o += MBW * 4;
  a.deg = (int*)(base + o); o += (size_t)N_NODES * 4;
  a.offn = (int*)(base + o); o += (size_t)N_NODES * 4;
  a.cur = (int*)(base + o); o += (size_t)N_NODES * 4;
  a.csr_se = (int2*)(base + o); o += (size_t)CAP_SLOTS * 8;
  a.csr_dst = (int*)(base + o); o += (size_t)CAP_SLOTS * 4;
  o = (o + 15) & ~(size_t)15;
  a.E2 = (int4*)(base + o); o += (size_t)CAP_E2 * 16;
  a.E3 = (int4*)(base + o); o += (size_t)CAP_E3 * 16;
  a.L1 = (int*)(base + o); o += (size_t)CAP_L1 * 4;
  a.L2 = (int*)(base + o); o += (size_t)CAP_L2 * 4;
  a.degf = (float*)(base + o); o += (size_t)CAP_L1 * 4;
  o = (o + 15) & ~(size_t)15;
  a.w1p = (u32*)(base + o); o += (size_t)NPK * 4;
  a.e1p = (u32*)(base + o); o += (size_t)NPK * 4;
  a.w2p = (u32*)(base + o); o += (size_t)NPK * 4;
  a.e2p = (u32*)(base + o); o += (size_t)NPK * 4;
  a.w3p = (u32*)(base + o); o += (size_t)NPK * 4;
  a.embp = (u32*)(base + o); o += (size_t)EMBP_U32 * 4;
  o = (o + 511) & ~(size_t)511;
  a.A_n = (u16*)(base + o); o += (size_t)CAP_L1 * 384 * 2;
  a.A_e = (u16*)(base + o); o += (size_t)CAP_E2 * 384 * 2;
  a.x1 = (float*)(base + o); o += (size_t)N_NODES * D * 4;
  a.x2 = (float*)(base + o); o += (size_t)N_NODES * D * 4;
  a.ea = (u16*)(base + o); o += (size_t)CAP_SLOTS * D * 2;

  // ---- try cooperative launch with an occupancy-derived grid ----
  bool launched = false;
  int occ = 0;
  hipError_t e = hipOccupancyMaxActiveBlocksPerMultiprocessor(
      &occ, (const void*)k_mega, 256, 0);
  if (e == hipSuccess && occ > 0) {
    long long grid = (long long)occ * 256;
    if (grid > 512) grid = 512;
    grid &= ~3LL;              // phases assume nb % 4 == 0
    if (grid >= 104) {         // P4 needs >= 98 blocks
      void* kp[] = {&a};
      if (hipLaunchCooperativeKernel((const void*)k_mega, dim3((u32)grid),
                                     dim3(256), kp, 0, stream) == hipSuccess)
        launched = true;
    }
  }

  // ---- fallback: identical phases as 13 kernels (kernel boundary = sync) ----
  if (!launched) {
    dim3 B(256);
    k_f_setup<<<640, B, 0, stream>>>(a);
    k_f_scan3<<<640, B, 0, stream>>>(a);
    k_f_scan2<<<640, B, 0, stream>>>(a);
    k_f_scan1<<<640, B, 0, stream>>>(a);
    k_f_alloc<<<98, B, 0, stream>>>(a);
    k_f_scatter<<<640, B, 0, stream>>>(a);
    k_f_lists<<<64, B, 0, stream>>>(a);
    k_f_gather1<<<1280, B, 0, stream>>>(a);
    k_f_gemm1<<<448, B, 0, stream>>>(a);
    k_f_gather2<<<192, B, 0, stream>>>(a);
    k_f_gemm2<<<128, B, 0, stream>>>(a);
    k_f_gather3<<<16, B, 0, stream>>>(a);
    k_f_gemm3<<<16, B, 0, stream>>>(a);
  }
}

// Round 16
// 489.426 us; speedup vs baseline: 1.0064x; 1.0064x over previous
//
#include <hip/hip_runtime.h>
#include <hip/hip_cooperative_groups.h>

namespace cg = cooperative_groups;

typedef unsigned short u16;
typedef unsigned int u32;
typedef unsigned long long u64;

#define N_NODES 100000
#define N_EDGES 600000
#define D 128
#define NPG 1000
#define NGRAPH 100
#define VOCAB 32000
#define MBW 3136          // mask words (padded) >= ceil(100000/32)

#define CAP_SLOTS 65536
#define CAP_L1    16384
#define CAP_L2    4096
#define CAP_E2    16384
#define CAP_E3    4096

#define C_SLOT 0
#define C_L1   1
#define C_L2   2
#define C_E2   3
#define C_E3   4
#define C64    8          // int-index of packed u64 alloc counter (8-aligned)

#define NPK (192 * 128)          // packed W u32 per job
#define EMBP_U32 (VOCAB * 64)    // bf16-packed embedding table, u32 count
#define ZWORDS (64 + 2 * MBW)    // ctrl + mb1 + mb2 in u32 words

__device__ __forceinline__ float bf2f(u16 u) {
  return __uint_as_float(((u32)u) << 16);
}
__device__ __forceinline__ u16 f2bf(float f) {
  u32 u = __float_as_uint(f);
  u32 r = (u + 0x7FFFu + ((u >> 16) & 1u)) >> 16;  // RNE
  return (u16)r;
}
__device__ __forceinline__ u32 packbf2(float a, float b) {
  return (u32)f2bf(a) | ((u32)f2bf(b) << 16);
}
__device__ __forceinline__ void fma4(float4& acc, float a, const float4 w) {
  acc.x = fmaf(a, w.x, acc.x);
  acc.y = fmaf(a, w.y, acc.y);
  acc.z = fmaf(a, w.z, acc.z);
  acc.w = fmaf(a, w.w, acc.w);
}
__device__ __forceinline__ float4 bf4(uint2 u) {
  return make_float4(bf2f((u16)(u.x & 0xFFFFu)), bf2f((u16)(u.x >> 16)),
                     bf2f((u16)(u.y & 0xFFFFu)), bf2f((u16)(u.y >> 16)));
}
__device__ __forceinline__ void add4(float4& a, const float4 b) {
  a.x += b.x; a.y += b.y; a.z += b.z; a.w += b.w;
}
__device__ __forceinline__ float4 shfl4(float4 v, int lane) {
  return make_float4(__shfl(v.x, lane, 32), __shfl(v.y, lane, 32),
                     __shfl(v.z, lane, 32), __shfl(v.w, lane, 32));
}
__device__ __forceinline__ int mbit(const u32* __restrict__ mb, int n) {
  return (mb[n >> 5] >> (n & 31)) & 1u;
}
__device__ __forceinline__ void mset(u32* __restrict__ mb, int n) {
  atomicOr(&mb[n >> 5], 1u << (n & 31));
}

struct MegaArgs {
  const int* tok;
  const int4* src4;
  const int4* dst4;
  const float* attr;
  const float* emb;
  const float* wproj;
  const float* bproj;
  const float *ws1, *bs1, *wm1, *bm1, *we1, *be1;
  const float *ws2, *bs2, *wm2, *bm2, *we2, *be2;
  const float *ws3, *bs3, *wm3, *bm3;
  float* out;
  int* ctrl;
  u32* mb1;
  u32* mb2;
  int* deg;
  int* offn;
  int* cur;
  int2* csr_se;
  int* csr_dst;
  int4* E2;
  int4* E3;
  int* L1;
  int* L2;
  float* degf;
  u32 *w1p, *e1p, *w2p, *e2p, *w3p;
  u32* embp;
  u16* A_n;
  u16* A_e;
  float* x1;
  float* x2;
  u16* ea;
};

// ================= phase device functions (shared by coop + fallback) =======

// P0: zero ctrl/masks/deg; pack 5 weight buffers + emb table to bf16
__device__ void ph_setup(const MegaArgs& A, int gtid, int nthr) {
  for (int i = gtid; i < ZWORDS; i += nthr) ((u32*)A.ctrl)[i] = 0;
  for (int i = gtid; i < N_NODES; i += nthr) A.deg[i] = 0;
  for (int t = gtid; t < 5 * NPK; t += nthr) {
    int buf = t / NPK, elem = t % NPK;
    int k2 = elem >> 7, c = elem & 127;
    int k0 = 2 * k2, k1 = 2 * k2 + 1;
    float a, b;
    u32* dst;
    if (buf == 0) {
      a = k0 < 128 ? A.ws1[k0 * 128 + c] : A.wm1[(k0 - 128) * 128 + c];
      b = k1 < 128 ? A.ws1[k1 * 128 + c] : A.wm1[(k1 - 128) * 128 + c];
      dst = A.w1p;
    } else if (buf == 1) {
      a = A.we1[k0 * 128 + c]; b = A.we1[k1 * 128 + c]; dst = A.e1p;
    } else if (buf == 2) {
      a = k0 < 128 ? A.ws2[k0 * 128 + c] : A.wm2[(k0 - 128) * 128 + c];
      b = k1 < 128 ? A.ws2[k1 * 128 + c] : A.wm2[(k1 - 128) * 128 + c];
      dst = A.w2p;
    } else if (buf == 3) {
      a = A.we2[k0 * 128 + c]; b = A.we2[k1 * 128 + c]; dst = A.e2p;
    } else {
      a = k0 < 128 ? A.ws3[k0 * 128 + c] : A.wm3[(k0 - 128) * 128 + c];
      b = k1 < 128 ? A.ws3[k1 * 128 + c] : A.wm3[(k1 - 128) * 128 + c];
      dst = A.w3p;
    }
    dst[elem] = packbf2(a, b);
  }
  for (int i = gtid; i < EMBP_U32; i += nthr) {
    float2 e2 = ((const float2*)A.emb)[i];
    A.embp[i] = packbf2(e2.x, e2.y);
  }
}

__device__ void ph_scan3(const MegaArgs& A, int gtid, int nthr) {
  if (gtid < NGRAPH) {
    mset(A.mb2, gtid * NPG);
    mset(A.mb1, gtid * NPG);
  }
  for (int i = gtid; i < N_EDGES / 4; i += nthr) {
    int4 d = A.dst4[i], s = A.src4[i];
    if (d.x % NPG == 0) { mset(A.mb2, s.x); mset(A.mb1, s.x); }
    if (d.y % NPG == 0) { mset(A.mb2, s.y); mset(A.mb1, s.y); }
    if (d.z % NPG == 0) { mset(A.mb2, s.z); mset(A.mb1, s.z); }
    if (d.w % NPG == 0) { mset(A.mb2, s.w); mset(A.mb1, s.w); }
  }
}

__device__ void ph_scan2(const MegaArgs& A, int gtid, int nthr) {
  for (int i = gtid; i < N_EDGES / 4; i += nthr) {
    int4 d = A.dst4[i], s = A.src4[i];
    if (mbit(A.mb2, d.x)) mset(A.mb1, s.x);
    if (mbit(A.mb2, d.y)) mset(A.mb1, s.y);
    if (mbit(A.mb2, d.z)) mset(A.mb1, s.z);
    if (mbit(A.mb2, d.w)) mset(A.mb1, s.w);
  }
}

__device__ void ph_scan1(const MegaArgs& A, int gtid, int nthr) {
  for (int i = gtid; i < N_EDGES / 4; i += nthr) {
    int4 d = A.dst4[i];
    if (mbit(A.mb1, d.x)) atomicAdd(&A.deg[d.x], 1);
    if (mbit(A.mb1, d.y)) atomicAdd(&A.deg[d.y], 1);
    if (mbit(A.mb1, d.z)) atomicAdd(&A.deg[d.z], 1);
    if (mbit(A.mb1, d.w)) atomicAdd(&A.deg[d.w], 1);
  }
}

// P4: CSR alloc — block bid handles nodes [bid*1024, bid*1024+1024), 4/thread,
// ONE packed-u64 atomic per block. ash = 16 shared ints.
__device__ void ph_alloc(const MegaArgs& A, int bid, int tid, int* ash) {
  int* asum = ash;       // [4] wave sums (then exclusive bases)
  int* acnt1 = ash + 4;
  int* acnt2 = ash + 8;
  int* abase = ash + 12; // [3]
  int lane = tid & 63, wid = tid >> 6;
  int base = bid * 1024 + tid * 4;
  bool m1v[4], m2v[4];
  int dv[4];
  int degs = 0, c1 = 0, c2 = 0;
#pragma unroll
  for (int j = 0; j < 4; ++j) {
    int n = base + j;
    bool in = n < N_NODES;
    m1v[j] = in && mbit(A.mb1, n);
    m2v[j] = in && mbit(A.mb2, n);
    dv[j] = m1v[j] ? A.deg[n] : 0;
    degs += dv[j];
    c1 += (int)m1v[j];
    c2 += (int)m2v[j];
  }
  int sI = degs, c1I = c1, c2I = c2;
#pragma unroll
  for (int o = 1; o < 64; o <<= 1) {
    int a = __shfl_up(sI, o, 64);
    int b = __shfl_up(c1I, o, 64);
    int c = __shfl_up(c2I, o, 64);
    if (lane >= o) { sI += a; c1I += b; c2I += c; }
  }
  if (lane == 63) { asum[wid] = sI; acnt1[wid] = c1I; acnt2[wid] = c2I; }
  __syncthreads();
  if (tid == 0) {
    int s0 = 0, s1 = 0, s2 = 0;
    int wb0[4], wb1[4], wb2[4];
#pragma unroll
    for (int w = 0; w < 4; ++w) {
      wb0[w] = s0; wb1[w] = s1; wb2[w] = s2;
      s0 += asum[w]; s1 += acnt1[w]; s2 += acnt2[w];
    }
    u64 pk = (u64)s0 | ((u64)s1 << 24) | ((u64)s2 << 44);
    u64 old = atomicAdd((u64*)(A.ctrl + C64), pk);
    abase[0] = (int)(old & 0xFFFFFF);
    abase[1] = (int)((old >> 24) & 0xFFFFF);
    abase[2] = (int)(old >> 44);
#pragma unroll
    for (int w = 0; w < 4; ++w) { asum[w] = wb0[w]; acnt1[w] = wb1[w]; acnt2[w] = wb2[w]; }
  }
  __syncthreads();
  int myoff = abase[0] + asum[wid] + (sI - degs);
  int myc1 = abase[1] + acnt1[wid] + (c1I - c1);
  int myc2 = abase[2] + acnt2[wid] + (c2I - c2);
#pragma unroll
  for (int j = 0; j < 4; ++j) {
    int n = base + j;
    if (m1v[j]) {
      A.offn[n] = myoff;
      A.cur[n] = myoff;
      myoff += dv[j];
      if (myc1 < CAP_L1) A.L1[myc1] = n;
      myc1++;
    }
    if (m2v[j]) {
      if (myc2 < CAP_L2) A.L2[myc2] = n;
      myc2++;
    }
  }
}

// P5: scatter edges into CSR (distributed cur atomics); thread 0 unpacks totals
__device__ void ph_scatter(const MegaArgs& A, int gtid, int nthr) {
  if (gtid == 0) {
    u64 pk = *(const u64*)(A.ctrl + C64);
    A.ctrl[C_SLOT] = (int)(pk & 0xFFFFFF);
    A.ctrl[C_L1] = (int)((pk >> 24) & 0xFFFFF);
    A.ctrl[C_L2] = (int)(pk >> 44);
  }
  for (int i = gtid; i < N_EDGES / 4; i += nthr) {
    int4 dv = A.dst4[i], sv = A.src4[i];
    int ds[4] = {dv.x, dv.y, dv.z, dv.w};
    int ss[4] = {sv.x, sv.y, sv.z, sv.w};
#pragma unroll
    for (int j = 0; j < 4; ++j) {
      int d = ds[j];
      if (!mbit(A.mb1, d)) continue;
      int p = atomicAdd(&A.cur[d], 1);
      if (p < CAP_SLOTS) {
        A.csr_se[p] = make_int2(ss[j], i * 4 + j);
        A.csr_dst[p] = d;
      }
    }
  }
}

// P6: build E2/E3 packed lists {p, src, dst, e}
__device__ void ph_lists(const MegaArgs& A, int gtid, int nthr) {
  int lane = threadIdx.x & 63;
  int ns = A.ctrl[C_SLOT];
  if (ns > CAP_SLOTS) ns = CAP_SLOTS;
  int total = (ns + 63) & ~63;
  for (int p = gtid; p < total; p += nthr) {
    bool inb = p < ns;
    int d = inb ? A.csr_dst[p] : 0;
    bool e2 = inb && mbit(A.mb2, d);
    bool e3 = inb && (d % NPG == 0);
    int2 se = (e2 || e3) ? A.csr_se[p] : make_int2(0, 0);
    u64 bal = __ballot(e2);
    if (bal) {
      int base = 0;
      if (lane == 0) base = atomicAdd(&A.ctrl[C_E2], __popcll(bal));
      base = __shfl(base, 0, 64);
      int pos = __popcll(bal & ((1ull << lane) - 1ull));
      if (e2 && base + pos < CAP_E2) A.E2[base + pos] = make_int4(p, se.x, d, se.y);
    }
    u64 bal3 = __ballot(e3);
    if (bal3) {
      int base = 0;
      if (lane == 0) base = atomicAdd(&A.ctrl[C_E3], __popcll(bal3));
      base = __shfl(base, 0, 64);
      int pos = __popcll(bal3 & ((1ull << lane) - 1ull));
      if (e3 && base + pos < CAP_E3) A.E3[base + pos] = make_int4(p, se.x, d, se.y);
    }
  }
}

// ---- gathers: build bf16 A rows ----

__device__ __forceinline__ void store_seg(u16* Ar, int seg, int q, float4 v) {
  ((uint2*)Ar)[seg * 32 + q] = make_uint2(packbf2(v.x, v.y), packbf2(v.z, v.w));
}

__device__ void dev_gather_node(const MegaArgs& A, bool l1, const int* L, int n_,
                                int relBlk, int nBlk, const float* xin, u16* An) {
  int sub = threadIdx.x >> 5, q = threadIdx.x & 31;
  for (int i = relBlk * 8 + sub; i < n_; i += nBlk * 8) {
    int n = L ? L[i] : i * NPG;
    int o = A.offn[n], end = A.cur[n];
    float dgf = (float)(end - o);
    float4 sx = make_float4(0.f, 0.f, 0.f, 0.f);
    float4 se = make_float4(0.f, 0.f, 0.f, 0.f);
    float4 xn;
    if (l1) {
      float4 sa = make_float4(0.f, 0.f, 0.f, 0.f);
      for (int p = o; p < end; ++p) {
        int2 s2 = A.csr_se[p];
        add4(sx, bf4(((const uint2*)A.embp)[(size_t)A.tok[s2.x] * 32 + q]));
        add4(sa, ((const float4*)(A.attr + (size_t)s2.y * 16))[q & 3]);
      }
      float4 bp = ((const float4*)A.bproj)[q];
      se = make_float4(bp.x * dgf, bp.y * dgf, bp.z * dgf, bp.w * dgf);
      const float4* wp = (const float4*)A.wproj;
#pragma unroll
      for (int k4 = 0; k4 < 4; ++k4) {
        float4 xv = shfl4(sa, k4);
        fma4(se, xv.x, wp[(k4 * 4 + 0) * 32 + q]);
        fma4(se, xv.y, wp[(k4 * 4 + 1) * 32 + q]);
        fma4(se, xv.z, wp[(k4 * 4 + 2) * 32 + q]);
        fma4(se, xv.w, wp[(k4 * 4 + 3) * 32 + q]);
      }
      xn = bf4(((const uint2*)A.embp)[(size_t)A.tok[n] * 32 + q]);
    } else {
      for (int p = o; p < end; ++p) {
        int s = A.csr_se[p].x;
        add4(sx, ((const float4*)(xin + (size_t)s * D))[q]);
        add4(se, bf4(((const uint2*)(A.ea + (size_t)p * D))[q]));
      }
      xn = ((const float4*)(xin + (size_t)n * D))[q];
    }
    u16* Ar = An + (size_t)i * 384;
    store_seg(Ar, 0, q, xn);
    store_seg(Ar, 1, q, sx);
    store_seg(Ar, 2, q, se);
    if (q == 0) A.degf[i] = dgf;
  }
}

__device__ void dev_gather_edge(const MegaArgs& A, bool l1, const int4* EL, int n_,
                                int relBlk, int nBlk, const float* xin, u16* Ae) {
  int sub = threadIdx.x >> 5, q = threadIdx.x & 31;
  for (int i = relBlk * 8 + sub; i < n_; i += nBlk * 8) {
    int4 t = EL[i];
    int p = t.x, s = t.y, d = t.z, e = t.w;
    float4 xd, xs, ev;
    if (l1) {
      xd = bf4(((const uint2*)A.embp)[(size_t)A.tok[d] * 32 + q]);
      xs = bf4(((const uint2*)A.embp)[(size_t)A.tok[s] * 32 + q]);
      float4 av = ((const float4*)(A.attr + (size_t)e * 16))[q & 3];
      ev = ((const float4*)A.bproj)[q];
      const float4* wp = (const float4*)A.wproj;
#pragma unroll
      for (int k4 = 0; k4 < 4; ++k4) {
        float4 xv = shfl4(av, k4);
        fma4(ev, xv.x, wp[(k4 * 4 + 0) * 32 + q]);
        fma4(ev, xv.y, wp[(k4 * 4 + 1) * 32 + q]);
        fma4(ev, xv.z, wp[(k4 * 4 + 2) * 32 + q]);
        fma4(ev, xv.w, wp[(k4 * 4 + 3) * 32 + q]);
      }
    } else {
      xd = ((const float4*)(xin + (size_t)d * D))[q];
      xs = ((const float4*)(xin + (size_t)s * D))[q];
      ev = bf4(((const uint2*)(A.ea + (size_t)p * D))[q]);
    }
    u16* Ar = Ae + (size_t)i * 384;
    store_seg(Ar, 0, q, xd);
    store_seg(Ar, 1, q, xs);
    store_seg(Ar, 2, q, ev);
  }
}

// ---- W-resident bf16 GEMM (one (job,col-half) per block) ----

#define ASF(x) __uint_as_float(x)

__device__ void dev_gemm(uint4* Wl4, uint4* Al4, const u16* Ab, const u32* W,
                         const float* biasp, const float* bmp, const float* degf,
                         const int* L, const int4* EL, float* outf, u16* outb,
                         int M, int relu, int half, int lid, int cnt) {
  int nt = (M + 15) >> 4;
  if (lid >= nt) return;   // block-uniform
  int q = threadIdx.x & 63, wv = threadIdx.x >> 6;
  const u32* Wlds = (const u32*)Wl4;
#pragma unroll
  for (int u = 0; u < 12; ++u) {
    int idx = threadIdx.x + u * 256;
    int k2 = idx >> 4, c4 = idx & 15;
    Wl4[idx] = ((const uint4*)W)[k2 * 32 + half * 16 + c4];
  }
  float bias = biasp[half * 64 + q];
  float bmv = degf ? bmp[half * 64 + q] : 0.f;
  for (int t = lid; t < nt; t += cnt) {
    __syncthreads();
#pragma unroll
    for (int u = 0; u < 3; ++u) {
      int idx = threadIdx.x + u * 256;
      int row = idx / 48, c8 = idx % 48;
      int gr = t * 16 + row;
      if (gr > M - 1) gr = M - 1;
      Al4[idx] = ((const uint4*)(Ab + (size_t)gr * 384))[c8];
    }
    __syncthreads();
    const uint2* A0 = (const uint2*)Al4 + (wv * 4 + 0) * 96;
    const uint2* A1 = (const uint2*)Al4 + (wv * 4 + 1) * 96;
    const uint2* A2 = (const uint2*)Al4 + (wv * 4 + 2) * 96;
    const uint2* A3 = (const uint2*)Al4 + (wv * 4 + 3) * 96;
    float acc0 = bias, acc1 = bias, acc2 = bias, acc3 = bias;
#pragma unroll 8
    for (int k4 = 0; k4 < 96; ++k4) {
      u32 wA = Wlds[(k4 * 2) * 64 + q];
      u32 wB = Wlds[(k4 * 2 + 1) * 64 + q];
      float wk0 = ASF(wA << 16), wk1 = ASF(wA & 0xffff0000u);
      float wk2 = ASF(wB << 16), wk3 = ASF(wB & 0xffff0000u);
      uint2 a;
      a = A0[k4];
      acc0 = fmaf(ASF(a.x << 16), wk0, acc0);
      acc0 = fmaf(ASF(a.x & 0xffff0000u), wk1, acc0);
      acc0 = fmaf(ASF(a.y << 16), wk2, acc0);
      acc0 = fmaf(ASF(a.y & 0xffff0000u), wk3, acc0);
      a = A1[k4];
      acc1 = fmaf(ASF(a.x << 16), wk0, acc1);
      acc1 = fmaf(ASF(a.x & 0xffff0000u), wk1, acc1);
      acc1 = fmaf(ASF(a.y << 16), wk2, acc1);
      acc1 = fmaf(ASF(a.y & 0xffff0000u), wk3, acc1);
      a = A2[k4];
      acc2 = fmaf(ASF(a.x << 16), wk0, acc2);
      acc2 = fmaf(ASF(a.x & 0xffff0000u), wk1, acc2);
      acc2 = fmaf(ASF(a.y << 16), wk2, acc2);
      acc2 = fmaf(ASF(a.y & 0xffff0000u), wk3, acc2);
      a = A3[k4];
      acc3 = fmaf(ASF(a.x << 16), wk0, acc3);
      acc3 = fmaf(ASF(a.x & 0xffff0000u), wk1, acc3);
      acc3 = fmaf(ASF(a.y << 16), wk2, acc3);
      acc3 = fmaf(ASF(a.y & 0xffff0000u), wk3, acc3);
    }
    float accs[4] = {acc0, acc1, acc2, acc3};
#pragma unroll
    for (int r = 0; r < 4; ++r) {
      int row = t * 16 + wv * 4 + r;
      if (row < M) {
        float a = accs[r];
        if (degf) a = fmaf(degf[row], bmv, a);
        if (relu) a = fmaxf(a, 0.f);
        if (outb) {
          int p = EL[row].x;
          outb[(size_t)p * D + half * 64 + q] = f2bf(a);
        } else {
          int idx = L ? L[row] : row;
          outf[(size_t)idx * D + half * 64 + q] = a;
        }
      }
    }
  }
}

// ---- per-stage wrappers ----

__device__ void ph_gather1(const MegaArgs& A, int bid, int nb) {
  int nL1 = A.ctrl[C_L1]; if (nL1 > CAP_L1) nL1 = CAP_L1;
  int nE2 = A.ctrl[C_E2]; if (nE2 > CAP_E2) nE2 = CAP_E2;
  int hf = nb >> 1;
  if (bid < hf) dev_gather_node(A, true, A.L1, nL1, bid, hf, nullptr, A.A_n);
  else dev_gather_edge(A, true, A.E2, nE2, bid - hf, nb - hf, nullptr, A.A_e);
}
__device__ void ph_gemm1(const MegaArgs& A, uint4* Wl4, uint4* Al4, int bid, int nb) {
  int nL1 = A.ctrl[C_L1]; if (nL1 > CAP_L1) nL1 = CAP_L1;
  int nE2 = A.ctrl[C_E2]; if (nE2 > CAP_E2) nE2 = CAP_E2;
  int job = (bid & 2) >> 1, half = bid & 1, lid = bid >> 2, cnt = nb >> 2;
  if (job == 0)
    dev_gemm(Wl4, Al4, A.A_n, A.w1p, A.bs1, A.bm1, A.degf, A.L1, nullptr,
             A.x1, nullptr, nL1, 1, half, lid, cnt);
  else
    dev_gemm(Wl4, Al4, A.A_e, A.e1p, A.be1, nullptr, nullptr, nullptr, A.E2,
             nullptr, A.ea, nE2, 1, half, lid, cnt);
}
__device__ void ph_gather2(const MegaArgs& A, int bid, int nb) {
  int nL2 = A.ctrl[C_L2]; if (nL2 > CAP_L2) nL2 = CAP_L2;
  int nE3 = A.ctrl[C_E3]; if (nE3 > CAP_E3) nE3 = CAP_E3;
  int hf = nb >> 1;
  if (bid < hf) dev_gather_node(A, false, A.L2, nL2, bid, hf, A.x1, A.A_n);
  else dev_gather_edge(A, false, A.E3, nE3, bid - hf, nb - hf, A.x1, A.A_e);
}
__device__ void ph_gemm2(const MegaArgs& A, uint4* Wl4, uint4* Al4, int bid, int nb) {
  int nL2 = A.ctrl[C_L2]; if (nL2 > CAP_L2) nL2 = CAP_L2;
  int nE3 = A.ctrl[C_E3]; if (nE3 > CAP_E3) nE3 = CAP_E3;
  int job = (bid & 2) >> 1, half = bid & 1, lid = bid >> 2, cnt = nb >> 2;
  if (job == 0)
    dev_gemm(Wl4, Al4, A.A_n, A.w2p, A.bs2, A.bm2, A.degf, A.L2, nullptr,
             A.x2, nullptr, nL2, 1, half, lid, cnt);
  else
    dev_gemm(Wl4, Al4, A.A_e, A.e2p, A.be2, nullptr, nullptr, nullptr, A.E3,
             nullptr, A.ea, nE3, 1, half, lid, cnt);
}
__device__ void ph_gather3(const MegaArgs& A, int bid, int nb) {
  int hf = nb >> 1;
  if (bid < hf) dev_gather_node(A, false, nullptr, NGRAPH, bid, hf, A.x2, A.A_n);
}
__device__ void ph_gemm3(const MegaArgs& A, uint4* Wl4, uint4* Al4, int bid, int nb) {
  int half = bid & 1, lid = bid >> 1, cnt = nb >> 1;
  dev_gemm(Wl4, Al4, A.A_n, A.w3p, A.bs3, A.bm3, A.degf, nullptr, nullptr,
           A.out, nullptr, NGRAPH, 0, half, lid, cnt);
}

// ================= cooperative mega-kernel =================

__global__ __launch_bounds__(256, 2) void k_mega(MegaArgs A) {
  __shared__ uint4 Wl4[3072];   // 48 KB
  __shared__ uint4 Al4[768];    // 12 KB
  __shared__ int ash[16];
  cg::grid_group grid = cg::this_grid();
  int tid = threadIdx.x, bid = blockIdx.x, nb = gridDim.x;
  int gtid = bid * 256 + tid, nthr = nb * 256;

  ph_setup(A, gtid, nthr);   grid.sync();
  ph_scan3(A, gtid, nthr);   grid.sync();
  ph_scan2(A, gtid, nthr);   grid.sync();
  ph_scan1(A, gtid, nthr);   grid.sync();
  if (bid < 98) ph_alloc(A, bid, tid, ash);
  grid.sync();
  ph_scatter(A, gtid, nthr); grid.sync();
  ph_lists(A, gtid, nthr);   grid.sync();
  ph_gather1(A, bid, nb);    grid.sync();
  ph_gemm1(A, Wl4, Al4, bid, nb); grid.sync();
  ph_gather2(A, bid, nb);    grid.sync();
  ph_gemm2(A, Wl4, Al4, bid, nb); grid.sync();
  ph_gather3(A, bid, nb);    grid.sync();
  ph_gemm3(A, Wl4, Al4, bid, nb);
}

// ================= fallback: phases as individual kernels =================

__global__ __launch_bounds__(256) void k_f_setup(MegaArgs A) {
  ph_setup(A, blockIdx.x * 256 + threadIdx.x, gridDim.x * 256);
}
__global__ __launch_bounds__(256) void k_f_scan3(MegaArgs A) {
  ph_scan3(A, blockIdx.x * 256 + threadIdx.x, gridDim.x * 256);
}
__global__ __launch_bounds__(256) void k_f_scan2(MegaArgs A) {
  ph_scan2(A, blockIdx.x * 256 + threadIdx.x, gridDim.x * 256);
}
__global__ __launch_bounds__(256) void k_f_scan1(MegaArgs A) {
  ph_scan1(A, blockIdx.x * 256 + threadIdx.x, gridDim.x * 256);
}
__global__ __launch_bounds__(256) void k_f_alloc(MegaArgs A) {  // grid = 98
  __shared__ int ash[16];
  ph_alloc(A, blockIdx.x, threadIdx.x, ash);
}
__global__ __launch_bounds__(256) void k_f_scatter(MegaArgs A) {
  ph_scatter(A, blockIdx.x * 256 + threadIdx.x, gridDim.x * 256);
}
__global__ __launch_bounds__(256) void k_f_lists(MegaArgs A) {
  ph_lists(A, blockIdx.x * 256 + threadIdx.x, gridDim.x * 256);
}
__global__ __launch_bounds__(256) void k_f_gather1(MegaArgs A) {
  ph_gather1(A, blockIdx.x, gridDim.x);
}
__global__ __launch_bounds__(256, 2) void k_f_gemm1(MegaArgs A) {
  __shared__ uint4 Wl4[3072];
  __shared__ uint4 Al4[768];
  ph_gemm1(A, Wl4, Al4, blockIdx.x, gridDim.x);
}
__global__ __launch_bounds__(256) void k_f_gather2(MegaArgs A) {
  ph_gather2(A, blockIdx.x, gridDim.x);
}
__global__ __launch_bounds__(256, 2) void k_f_gemm2(MegaArgs A) {
  __shared__ uint4 Wl4[3072];
  __shared__ uint4 Al4[768];
  ph_gemm2(A, Wl4, Al4, blockIdx.x, gridDim.x);
}
__global__ __launch_bounds__(256) void k_f_gather3(MegaArgs A) {
  ph_gather3(A, blockIdx.x, gridDim.x);
}
__global__ __launch_bounds__(256, 2) void k_f_gemm3(MegaArgs A) {
  __shared__ uint4 Wl4[3072];
  __shared__ uint4 Al4[768];
  ph_gemm3(A, Wl4, Al4, blockIdx.x, gridDim.x);
}

extern "C" void kernel_launch(void* const* d_in, const int* in_sizes, int n_in,
                              void* d_out, int out_size, void* d_ws, size_t ws_size,
                              hipStream_t stream) {
  MegaArgs a;
  a.tok = (const int*)d_in[0];
  const int* eidx = (const int*)d_in[1];
  a.src4 = (const int4*)eidx;
  a.dst4 = (const int4*)(eidx + N_EDGES);
  a.attr = (const float*)d_in[2];
  a.emb = (const float*)d_in[4];
  a.wproj = (const float*)d_in[5];
  a.bproj = (const float*)d_in[6];
  a.ws1 = (const float*)d_in[7];  a.bs1 = (const float*)d_in[8];
  a.wm1 = (const float*)d_in[9];  a.bm1 = (const float*)d_in[10];
  a.we1 = (const float*)d_in[11]; a.be1 = (const float*)d_in[12];
  a.ws2 = (const float*)d_in[13]; a.bs2 = (const float*)d_in[14];
  a.wm2 = (const float*)d_in[15]; a.bm2 = (const float*)d_in[16];
  a.we2 = (const float*)d_in[17]; a.be2 = (const float*)d_in[18];
  a.ws3 = (const float*)d_in[19]; a.bs3 = (const float*)d_in[20];
  a.wm3 = (const float*)d_in[21]; a.bm3 = (const float*)d_in[22];
  a.out = (float*)d_out;

  char* base = (char*)d_ws;
  size_t o = 0;
  a.ctrl = (int*)(base + o); o += 256;
  a.mb1 = (u32*)(base + o); o += MBW * 4;
  a.mb2 = (u32*)(base + o); o += MBW * 4;
  a.deg = (int*)(base + o); o += (size_t)N_NODES * 4;
  a.offn = (int*)(base + o); o += (size_t)N_NODES * 4;
  a.cur = (int*)(base + o); o += (size_t)N_NODES * 4;
  a.csr_se = (int2*)(base + o); o += (size_t)CAP_SLOTS * 8;
  a.csr_dst = (int*)(base + o); o += (size_t)CAP_SLOTS * 4;
  o = (o + 15) & ~(size_t)15;
  a.E2 = (int4*)(base + o); o += (size_t)CAP_E2 * 16;
  a.E3 = (int4*)(base + o); o += (size_t)CAP_E3 * 16;
  a.L1 = (int*)(base + o); o += (size_t)CAP_L1 * 4;
  a.L2 = (int*)(base + o); o += (size_t)CAP_L2 * 4;
  a.degf = (float*)(base + o); o += (size_t)CAP_L1 * 4;
  o = (o + 15) & ~(size_t)15;
  a.w1p = (u32*)(base + o); o += (size_t)NPK * 4;
  a.e1p = (u32*)(base + o); o += (size_t)NPK * 4;
  a.w2p = (u32*)(base + o); o += (size_t)NPK * 4;
  a.e2p = (u32*)(base + o); o += (size_t)NPK * 4;
  a.w3p = (u32*)(base + o); o += (size_t)NPK * 4;
  a.embp = (u32*)(base + o); o += (size_t)EMBP_U32 * 4;
  o = (o + 511) & ~(size_t)511;
  a.A_n = (u16*)(base + o); o += (size_t)CAP_L1 * 384 * 2;
  a.A_e = (u16*)(base + o); o += (size_t)CAP_E2 * 384 * 2;
  a.x1 = (float*)(base + o); o += (size_t)N_NODES * D * 4;
  a.x2 = (float*)(base + o); o += (size_t)N_NODES * D * 4;
  a.ea = (u16*)(base + o); o += (size_t)CAP_SLOTS * D * 2;

  // ---- try cooperative launch with an occupancy-derived grid ----
  bool launched = false;
  int occ = 0;
  hipError_t e = hipOccupancyMaxActiveBlocksPerMultiprocessor(
      &occ, (const void*)k_mega, 256, 0);
  if (e == hipSuccess && occ > 0) {
    long long grid = (long long)occ * 256;
    if (grid > 512) grid = 512;
    grid &= ~3LL;              // phases assume nb % 4 == 0
    if (grid >= 104) {         // P4 needs >= 98 blocks
      void* kp[] = {&a};
      if (hipLaunchCooperativeKernel((const void*)k_mega, dim3((u32)grid),
                                     dim3(256), kp, 0, stream) == hipSuccess)
        launched = true;
    }
  }

  // ---- fallback: identical phases as 13 kernels (kernel boundary = sync) ----
  if (!launched) {
    dim3 B(256);
    k_f_setup<<<640, B, 0, stream>>>(a);
    k_f_scan3<<<640, B, 0, stream>>>(a);
    k_f_scan2<<<640, B, 0, stream>>>(a);
    k_f_scan1<<<640, B, 0, stream>>>(a);
    k_f_alloc<<<98, B, 0, stream>>>(a);
    k_f_scatter<<<640, B, 0, stream>>>(a);
    k_f_lists<<<64, B, 0, stream>>>(a);
    k_f_gather1<<<1280, B, 0, stream>>>(a);
    k_f_gemm1<<<448, B, 0, stream>>>(a);
    k_f_gather2<<<192, B, 0, stream>>>(a);
    k_f_gemm2<<<128, B, 0, stream>>>(a);
    k_f_gather3<<<16, B, 0, stream>>>(a);
    k_f_gemm3<<<16, B, 0, stream>>>(a);
  }
}